// Round 10
// baseline (284.369 us; speedup 1.0000x reference)
//
#include <hip/hip_runtime.h>

// MSA conv2d-like QK correlation. B=8, C=128, H=W=128, fp32.
// out[b, i*3+j, h, w] = sum_c Q[b,c,h,w] * K[b,c,h+i-1,w+j-1]  (zero-padded)
//
// Round 10: R9's pure-stream probe measured the REAL read ceiling for this
// harness: 2.95 TB/s (45.5us for 134MB), invariant to HBM-vs-L3 sourcing
// (replays are fully L3-resident, FETCH~0). The R4 conv at 2.77 TB/s
// combined was already at 94% of it. Remaining headroom is BYTES, not rate:
// kill the 42.5MB of partial-sum traffic (conv 53us + reduce 6us) with a
// single kernel doing the C-split INSIDE the block.
// Geometry: 512-thr block = 8 waves; wave g reduces channels [16g,16g+16)
// for the same (b, 2-row x 128-w) tile. Inner loop = R4's float4+shfl form,
// fully unrolled (compiler clusters loads under the 128-VGPR budget).
// Cross-wave combine: staggered LDS binary tree, buf[2][36][65] (bank
// (i+s)%32 -> 2-way, conflict-free), 7 barriers. Wave 0 masks + stores.
// Grid 64x8 = 512 blocks = 4096 waves = 16/CU (2 blocks/CU).
// Traffic: 128MB in + 4.6MB out = 132.6MB -> predict 46-52us at probe rate.

#define Bn 8
#define Cn 128
#define Hn 128
#define Wn 128
#define HWn (Hn * Wn)
#define NG 8           // c-groups = waves per block
#define CG (Cn / NG)   // 16 channels per group

__global__ __launch_bounds__(512, 4) void msa_conv_v7(
    const float* __restrict__ Q, const float* __restrict__ K,
    float* __restrict__ out) {
  // Reduction buffer: word addr = i*65 + s -> bank (i+s)%32: for fixed i,
  // 64 lanes hit each bank exactly twice (2-way = free, m136). Non-contiguous
  // per-lane layout also stops the compiler from merging into b128 writes
  // (which would re-introduce conflicts).
  __shared__ float buf[2][36][65];  // 18.7 KB

  const int tid = threadIdx.x;  // 0..511
  const int cg  = tid >> 6;     // wave id = c-group 0..7
  const int s   = tid & 63;     // slot within tile (lane)
  const int wq  = s & 31;       // float4 column; w0 = 4*wq
  const int rr  = s >> 5;       // row within tile 0..1
  const int w0  = wq * 4;
  const int r0  = blockIdx.x * 2;
  const int r   = r0 + rr;      // output row
  const int b   = blockIdx.y;

  // Mirror-clamped neighbor rows (OOB -> in-bounds dummy; taps zeroed at the
  // store). Every global address stays inside the allocation.
  const int rm = (r > 0) ? r - 1 : r + 1;
  const int rp = (r < Hn - 1) ? r + 1 : r - 1;

  const size_t base = ((size_t)b * Cn + (size_t)cg * CG) * HWn;
  const float* qp = Q + base + (size_t)r  * Wn + w0;
  const float* mp = K + base + (size_t)rm * Wn + w0;
  const float* zp = K + base + (size_t)r  * Wn + w0;
  const float* pp = K + base + (size_t)rp * Wn + w0;

  float acc[9][4] = {};

#define ACC4(t, s0, s1, s2, s3) \
  acc[t][0] += q4.x * (s0);     \
  acc[t][1] += q4.y * (s1);     \
  acc[t][2] += q4.z * (s2);     \
  acc[t][3] += q4.w * (s3);

#pragma unroll
  for (int c = 0; c < CG; ++c) {
    const float4 q4 = *(const float4*)qp;
    const float4 m4 = *(const float4*)mp;
    const float4 z4 = *(const float4*)zp;
    const float4 p4 = *(const float4*)pp;
    // Wave layout: lanes 0-31 = row rr=0, lanes 32-63 = rr=1; +-1-lane
    // shuffles move along w. wq==0 / wq==31 lanes receive garbage in exactly
    // the components masked before the store.
    const float mL = __shfl_up(m4.w, 1, 64);
    const float zL = __shfl_up(z4.w, 1, 64);
    const float pL = __shfl_up(p4.w, 1, 64);
    const float mR = __shfl_down(m4.x, 1, 64);
    const float zR = __shfl_down(z4.x, 1, 64);
    const float pR = __shfl_down(p4.x, 1, 64);

    ACC4(0, mL,   m4.x, m4.y, m4.z)   // i=-1, j=-1
    ACC4(1, m4.x, m4.y, m4.z, m4.w)   // i=-1, j= 0
    ACC4(2, m4.y, m4.z, m4.w, mR)     // i=-1, j=+1
    ACC4(3, zL,   z4.x, z4.y, z4.z)   // i= 0, j=-1
    ACC4(4, z4.x, z4.y, z4.z, z4.w)   // i= 0, j= 0
    ACC4(5, z4.y, z4.z, z4.w, zR)     // i= 0, j=+1
    ACC4(6, pL,   p4.x, p4.y, p4.z)   // i=+1, j=-1
    ACC4(7, p4.x, p4.y, p4.z, p4.w)   // i=+1, j= 0
    ACC4(8, p4.y, p4.z, p4.w, pR)     // i=+1, j=+1

    qp += HWn; mp += HWn; zp += HWn; pp += HWn;
  }
#undef ACC4

  // ---- staggered binary-tree reduction over the 8 c-groups ----
  // A: g0+=g4, g1+=g5; B: g2+=g6, g3+=g7; C: g0+=g2, g1+=g3; D: g0+=g1.
#define WRITE(p)                                              \
  do {                                                        \
    _Pragma("unroll") for (int t = 0; t < 9; ++t)             \
    _Pragma("unroll") for (int k = 0; k < 4; ++k)             \
        buf[p][t * 4 + k][s] = acc[t][k];                     \
  } while (0)
#define ADD(p)                                                \
  do {                                                        \
    _Pragma("unroll") for (int t = 0; t < 9; ++t)             \
    _Pragma("unroll") for (int k = 0; k < 4; ++k)             \
        acc[t][k] += buf[p][t * 4 + k][s];                    \
  } while (0)

  if (cg == 4) WRITE(0);
  if (cg == 5) WRITE(1);
  __syncthreads();
  if (cg == 0) ADD(0);
  if (cg == 1) ADD(1);
  __syncthreads();
  if (cg == 6) WRITE(0);
  if (cg == 7) WRITE(1);
  __syncthreads();
  if (cg == 2) ADD(0);
  if (cg == 3) ADD(1);
  __syncthreads();
  if (cg == 2) WRITE(0);
  if (cg == 3) WRITE(1);
  __syncthreads();
  if (cg == 0) ADD(0);
  if (cg == 1) ADD(1);
  __syncthreads();
  if (cg == 1) WRITE(0);
  __syncthreads();

  if (cg == 0) {
    ADD(0);
    // Epilogue masking: OOB taps/components have fully-zero C-sums in the
    // reference (zero padding).
    if (wq == 0)  { acc[0][0] = 0.f; acc[3][0] = 0.f; acc[6][0] = 0.f; }
    if (wq == 31) { acc[2][3] = 0.f; acc[5][3] = 0.f; acc[8][3] = 0.f; }
    if (r == 0) {
#pragma unroll
      for (int t = 0; t < 3; ++t)
#pragma unroll
        for (int k = 0; k < 4; ++k) acc[t][k] = 0.f;
    }
    if (r == Hn - 1) {
#pragma unroll
      for (int t = 6; t < 9; ++t)
#pragma unroll
        for (int k = 0; k < 4; ++k) acc[t][k] = 0.f;
    }

    float* o = out + (size_t)b * 9 * HWn + (size_t)r * Wn + w0;
#pragma unroll
    for (int t = 0; t < 9; ++t)
      *(float4*)(o + (size_t)t * HWn) =
          make_float4(acc[t][0], acc[t][1], acc[t][2], acc[t][3]);
  }
#undef WRITE
#undef ADD
}

extern "C" void kernel_launch(void* const* d_in, const int* in_sizes, int n_in,
                              void* d_out, int out_size, void* d_ws,
                              size_t ws_size, hipStream_t stream) {
  const float* Q = (const float*)d_in[0];
  const float* K = (const float*)d_in[1];
  float* out = (float*)d_out;

  dim3 block(512);
  dim3 grid(Hn / 2, Bn);  // 64 x 8 = 512 blocks = 4096 waves = 16/CU
  msa_conv_v7<<<grid, block, 0, stream>>>(Q, K, out);
}